// Round 8
// baseline (897.169 us; speedup 1.0000x reference)
//
#include <hip/hip_runtime.h>
#include <cmath>

#define NB 512            // 16 batch groups x 32 unit blocks; 2 blocks/CU (TLP over exchange RT)
#define NT 256
#define NG 16             // batch groups
#define GB 32             // blocks per group
#define B_ 256
#define T_ 256
#define I_ 64
#define H_ 512
#define G4H 2048
#define BT 16             // batch rows per block
#define UT 16             // hidden units per block -> 64 z cols, 4 waves (1 gate each)
#define ZP 68             // zs row stride (64 + 4)
#define NFC 18            // K chunks of 32
#define CPQ 17            // cells (16B) per q-group: 16 rows + 1 pad
#define CSTR 68           // cell stride per chunk (4*17)
#define NCELL 1224        // 18*68
#define KTN (T_ * UT)     // time-gate table entries
#define R_ON_F 0.05f
#define ALPHA_F 1.0e-3f
#define LN_EPS_F 1.0e-5f

typedef _Float16 h8 __attribute__((ext_vector_type(8)));
typedef _Float16 h4v __attribute__((ext_vector_type(4)));
typedef float f4 __attribute__((ext_vector_type(4)));
typedef unsigned u4 __attribute__((ext_vector_type(4)));
typedef unsigned short us4 __attribute__((ext_vector_type(4)));

// Packed hidden-state double buffer: fp16(h)<<16 | (launch_tag<<8 | t+1).
// DEVICE SCOPE ONLY (sc0 sc1): R4/R5 proved XCD co-location can't be assumed
// and L2-scope polling reads stale clean lines forever.
// Launch-tagged epochs (verified R7): stale data never equality-matches ->
// no zeroing, no startup barrier. NB=512 now => tag = cnt>>9.
// STORE LAYOUT (R6 lesson): h-stores must stay contiguous per row. UT=16
// gives 64B aligned segments (16 units x 4B) -- sector-aligned, predicted
// safe; WRITE_SIZE is the kill-switch.
__device__ __align__(16) unsigned g_hp[2][B_ * H_];
// Exact fp32 final h for the LN/dense epilogue (written only at t = T_-1).
__device__ __align__(16) float g_hf[B_ * H_];

struct alignas(256) PadCnt { unsigned v; unsigned pad[63]; };
__device__ PadCnt g_flag[NG][GB];   // FINAL handoff only; tagged values
__device__ unsigned g_launch_cnt;   // never reset; +NB per launch => tag = cnt>>9

__device__ __forceinline__ float fast_sigmoid(float x) {
    return __builtin_amdgcn_rcpf(1.f + __expf(-x));
}
__device__ __forceinline__ float fast_tanh(float x) {
    return 1.f - 2.f * __builtin_amdgcn_rcpf(__expf(2.f * x) + 1.f);
}

struct HiLo { _Float16 hi, lo; };
__device__ __forceinline__ HiLo cvt_hilo(float v) {
    HiLo r;
    r.hi = (_Float16)v;
    r.lo = (_Float16)(v - (float)r.hi);
    return r;
}

__global__ __launch_bounds__(NT, 2) void plstm_scan_kernel(
    const float* __restrict__ x, const float* __restrict__ W,
    const float* __restrict__ U, const float* __restrict__ bias,
    const float* __restrict__ tau, const float* __restrict__ sph,
    const float* __restrict__ ln_g, const float* __restrict__ ln_b,
    const float* __restrict__ W1, const float* __restrict__ b1,
    const float* __restrict__ W2, const float* __restrict__ b2,
    float* __restrict__ out)
{
    __shared__ __align__(16) _Float16 Ah[NCELL * 8];   // 19.1 KB A (fp16 hi), fragment order
    __shared__ __align__(16) float zs[BT][ZP];         // 4.25 KB z tile
    __shared__ __align__(16) float kt[KTN];            // 16 KB time-gate table
    __shared__ float red[16];
    __shared__ unsigned s_tag;
    __shared__ char padlds[16384];  // occupancy clamp: LDS ~56KB -> exactly 2 blocks/CU

    const int tid = threadIdx.x;
    const int bt = blockIdx.x >> 5;    // batch group 0..15
    const int ut = blockIdx.x & 31;    // unit block 0..31
    const int b0 = bt * BT;
    const int u0 = ut * UT;

    if (tid == 0) s_tag = (atomicAdd(&g_launch_cnt, 1u) >> 9) + 1u;

    const int wv = tid >> 6;           // wave 0..3 = gate 0..3
    const int lane = tid & 63;
    const int n_ = lane & 15;
    const int q_ = lane >> 4;

    // ---- one-time: B fragments. Wave wv owns gate wv, units u0..u0+15 ----
    const int jg = wv * H_ + u0 + n_;
    h8 Bh[NFC], Bl[NFC];
    #pragma unroll
    for (int c = 0; c < NFC; ++c) {
        #pragma unroll
        for (int e = 0; e < 8; ++e) {
            const int kk = c * 32 + q_ * 8 + e;
            float v;
            if (c < 2) v = W[(size_t)kk * G4H + jg];
            else       v = U[(size_t)(kk - I_) * G4H + jg];
            const HiLo hl = cvt_hilo(v);
            Bh[c][e] = hl.hi;
            Bl[c][e] = hl.lo;
        }
    }
    const float bv = bias[jg];         // bias folded into MFMA C-input

    // ---- one-time: time-gate table k[t][unit_local] ----
    for (int idx = tid; idx < KTN; idx += NT) {
        const int tt = idx >> 4, ul = idx & 15;
        const float ta = tau[u0 + ul];
        float aa = (float)tt - sph[u0 + ul];
        float rr = fmodf(aa, ta);
        if (rr < 0.f) rr += ta;
        const float phi = rr / ta;
        float kk;
        if (phi < 0.5f * R_ON_F)      kk = phi * (2.f / R_ON_F);
        else if (phi < R_ON_F)        kk = 2.f - phi * (2.f / R_ON_F);
        else                          kk = ALPHA_F * phi;
        kt[idx] = kk;
    }
    __syncthreads();                   // publish s_tag + kt
    const unsigned tagw = s_tag;
    const unsigned tagb = (tagw & 0xFFu) << 8;
    if (tagw == 0xFFFFFFFFu) padlds[0] = 1;   // keep pad allocated (never true)

    // gate-update layout: 256 threads -> (row 0..15, unit 0..15)
    const int urow = tid >> 4;
    const int uu   = tid & 15;
    float c_st = 0.f;
    float h_st = 0.f;   // exact fp32 hprev: pure per-thread recurrence

    // staging geometry
    const int xr = tid >> 4, xc4 = (tid & 15) << 2;         // x: 1 float4/thread
    const int cX = (tid & 15) >> 3, qX = ((tid & 15) >> 1) & 3;
    const int e0x = (tid & 1) << 2;
    const int fX = (cX * CSTR + qX * CPQ + xr) * 8 + e0x;
    const int m = tid & 127;                                // h: 8 rows x 4 packed cols
    const int hr0 = tid >> 7;                               // 0..1
    const int hk4 = m << 2;
    const int cS = 2 + (m >> 3), qS = (m >> 1) & 3;
    const int e0 = (m & 1) << 2;

    float4 xv = *(const float4*)(x + ((size_t)(b0 + xr) * T_ + 0) * I_ + xc4);

    // MFMA A-frag read base (fragment order; same A broadcast to all 4 waves)
    const int fb = (q_ * CPQ + n_) * 8;

    int cur = 0;
    for (int t = 0; t < T_; ++t) {
        // ---- A) stage operands (tag-exact epoch poll, device scope) ----
        if (t == 0) {
            const h8 z8 = {};
            for (int idx = tid; idx < NCELL; idx += NT)
                *(h8*)&Ah[idx * 8] = z8;
            __syncthreads();
            {
                h4v xh;
                xh[0] = (_Float16)xv.x; xh[1] = (_Float16)xv.y;
                xh[2] = (_Float16)xv.z; xh[3] = (_Float16)xv.w;
                *(h4v*)&Ah[fX] = xh;
            }
        } else {
            const unsigned* hb = g_hp[cur] + (size_t)(b0 + hr0) * H_ + hk4;
            const unsigned want = tagb | (unsigned)t;
            u4 a0, a1, a2, a3, a4, a5, a6, a7;
            bool ok;
            auto chk = [&](const u4& v) {
                return ((v[0] & 0xFFFFu) == want) & ((v[1] & 0xFFFFu) == want)
                     & ((v[2] & 0xFFFFu) == want) & ((v[3] & 0xFFFFu) == want);
            };
            do {
                asm volatile(
                    "global_load_dwordx4 %0, %8, off sc0 sc1\n\t"
                    "global_load_dwordx4 %1, %9, off sc0 sc1\n\t"
                    "global_load_dwordx4 %2, %10, off sc0 sc1\n\t"
                    "global_load_dwordx4 %3, %11, off sc0 sc1\n\t"
                    "global_load_dwordx4 %4, %12, off sc0 sc1\n\t"
                    "global_load_dwordx4 %5, %13, off sc0 sc1\n\t"
                    "global_load_dwordx4 %6, %14, off sc0 sc1\n\t"
                    "global_load_dwordx4 %7, %15, off sc0 sc1\n\t"
                    "s_waitcnt vmcnt(0)"
                    : "=&v"(a0), "=&v"(a1), "=&v"(a2), "=&v"(a3),
                      "=&v"(a4), "=&v"(a5), "=&v"(a6), "=&v"(a7)
                    : "v"(hb), "v"(hb + 2 * H_), "v"(hb + 4 * H_), "v"(hb + 6 * H_),
                      "v"(hb + 8 * H_), "v"(hb + 10 * H_), "v"(hb + 12 * H_), "v"(hb + 14 * H_)
                    : "memory");
                ok = chk(a0) & chk(a1) & chk(a2) & chk(a3)
                   & chk(a4) & chk(a5) & chk(a6) & chk(a7);
            } while (__ballot(!ok));
            const u4 av[8] = {a0, a1, a2, a3, a4, a5, a6, a7};
            #pragma unroll
            for (int i = 0; i < 8; ++i) {
                const int row = hr0 + 2 * i;
                const int fidx = (cS * CSTR + qS * CPQ + row) * 8 + e0;
                us4 uv;
                uv[0] = (unsigned short)(av[i][0] >> 16);
                uv[1] = (unsigned short)(av[i][1] >> 16);
                uv[2] = (unsigned short)(av[i][2] >> 16);
                uv[3] = (unsigned short)(av[i][3] >> 16);
                *(us4*)&Ah[fidx] = uv;   // fp16 payload, writer already converted
            }
        }
        __syncthreads();                                   // S1

        // prefetch next x
        {
            const int tn = (t < T_ - 1) ? t + 1 : t;
            xv = *(const float4*)(x + ((size_t)(b0 + xr) * T_ + tn) * I_ + xc4);
        }

        // ---- B) MFMA: A-hi x (B-hi + B-lo), bias as C-in ----
        f4 ac0 = {bv, bv, bv, bv};
        f4 ac1 = {0.f, 0.f, 0.f, 0.f};
        #pragma unroll
        for (int c = 0; c < NFC; ++c) {
            const h8 ah = *(const h8*)&Ah[fb + c * (CSTR * 8)];
            ac0 = __builtin_amdgcn_mfma_f32_16x16x32_f16(ah, Bh[c], ac0, 0, 0, 0);
            ac1 = __builtin_amdgcn_mfma_f32_16x16x32_f16(ah, Bl[c], ac1, 0, 0, 0);
        }
        const f4 zt = ac0 + ac1;
        {
            const int colz = wv * 16 + n_;     // gate-major: gate wv cols 16wv..16wv+15
            const int rz = q_ * 4;             // C-layout: row=(lane>>4)*4+reg (M=16)
            zs[rz + 0][colz] = zt[0];
            zs[rz + 1][colz] = zt[1];
            zs[rz + 2][colz] = zt[2];
            zs[rz + 3][colz] = zt[3];
        }
        __syncthreads();                                   // S2

        // ---- C) gates + table time-gate; tagged h store (64B row segments) ----
        {
            const float zi = zs[urow][uu];
            const float zf = zs[urow][16 + uu];
            const float zg = zs[urow][32 + uu];
            const float zo = zs[urow][48 + uu];
            const float si = fast_sigmoid(zi);
            const float sf = fast_sigmoid(zf);
            const float so = fast_sigmoid(zo);
            const float ct = sf * c_st + si * fast_tanh(zg);
            const float ht = so * fast_tanh(ct);
            const float kk = kt[(t << 4) + uu];
            const float hn = kk * ht + (1.f - kk) * h_st;
            c_st = kk * ct + (1.f - kk) * c_st;
            h_st = hn;
            if (t < T_ - 1) {
                const unsigned short hb16 = __builtin_bit_cast(unsigned short, (_Float16)hn);
                const unsigned packed = ((unsigned)hb16 << 16) | (tagb | (unsigned)(t + 1));
                unsigned* gp = g_hp[cur ^ 1] + (size_t)(b0 + urow) * H_ + (u0 + uu);
                asm volatile("global_store_dword %0, %1, off sc0 sc1"
                             :: "v"(gp), "v"(packed) : "memory");
            } else {
                float* gp = g_hf + (size_t)(b0 + urow) * H_ + (u0 + uu);
                asm volatile("global_store_dword %0, %1, off sc0 sc1\n\ts_waitcnt vmcnt(0)"
                             :: "v"(gp), "v"(hn) : "memory");
            }
        }

        // ---- final-step handoff: drain + barrier + tagged flag publish ----
        if (t == T_ - 1) {
            __syncthreads();
            if (tid == 0) {
                unsigned fv = (tagw << 8) | 0xFFu;
                asm volatile("global_store_dword %0, %1, off sc0 sc1"
                             :: "v"(&g_flag[bt][ut].v), "v"(fv) : "memory");
            }
        }

        // ---- D) overlapped x staging ----
        if (t < T_ - 1) {
            h4v xh;
            xh[0] = (_Float16)xv.x; xh[1] = (_Float16)xv.y;
            xh[2] = (_Float16)xv.z; xh[3] = (_Float16)xv.w;
            *(h4v*)&Ah[fX] = xh;
        }
        cur ^= 1;
    }

    // ---- epilogue: blocks ut<16 handle batch row b0+ut (2 units/thread) ----
    if (ut < 16) {
        if (tid < 64) {
            const unsigned want = (tagw << 8) | 0xFFu;
            const unsigned* fp = &g_flag[bt][tid & 31].v;
            unsigned v;
            do {
                asm volatile("global_load_dword %0, %1, off sc0 sc1\n\ts_waitcnt vmcnt(0)"
                             : "=v"(v) : "v"(fp) : "memory");
            } while (__ballot(v != want));
        }
        __syncthreads();

        const int r = b0 + ut;         // bijective over [0,256)
        float hv0, hv1;
        const float* hp = g_hf + (size_t)r * H_ + tid;
        asm volatile("global_load_dword %0, %2, off sc0 sc1\n\t"
                     "global_load_dword %1, %3, off sc0 sc1\n\t"
                     "s_waitcnt vmcnt(0)"
                     : "=&v"(hv0), "=&v"(hv1) : "v"(hp), "v"(hp + 256) : "memory");
        float s1 = hv0 + hv1, s2 = hv0 * hv0 + hv1 * hv1;
        #pragma unroll
        for (int off = 32; off > 0; off >>= 1) {
            s1 += __shfl_down(s1, off, 64);
            s2 += __shfl_down(s2, off, 64);
        }
        const int ln = tid & 63;
        if (ln == 0) { red[wv] = s1; red[8 + wv] = s2; }
        __syncthreads();
        float S1 = 0.f, S2 = 0.f;
        #pragma unroll
        for (int w = 0; w < 4; ++w) { S1 += red[w]; S2 += red[8 + w]; }
        const float mu = S1 * (1.f / 512.f);
        const float var = S2 * (1.f / 512.f) - mu * mu;
        const float rstd = rsqrtf(var + LN_EPS_F);
        const float hn0 = (hv0 - mu) * rstd * ln_g[tid] + ln_b[tid];
        const float hn1 = (hv1 - mu) * rstd * ln_g[tid + 256] + ln_b[tid + 256];
        float w12a = 0.f, w12b = 0.f;
        const float* w1p = W1 + (size_t)tid * 256;
        const float* w1q = W1 + (size_t)(tid + 256) * 256;
        #pragma unroll 4
        for (int d = 0; d < 256; ++d) {
            w12a = fmaf(w1p[d], W2[d], w12a);
            w12b = fmaf(w1q[d], W2[d], w12b);
        }
        float contrib = hn0 * w12a + hn1 * w12b + b1[tid] * W2[tid];
        #pragma unroll
        for (int off = 32; off > 0; off >>= 1) contrib += __shfl_down(contrib, off, 64);
        __syncthreads();
        if (ln == 0) red[wv] = contrib;
        __syncthreads();
        if (tid == 0) {
            float tot = b2[0];
            #pragma unroll
            for (int w = 0; w < 4; ++w) tot += red[w];
            out[r] = tot;
        }
    }
}

extern "C" void kernel_launch(void* const* d_in, const int* in_sizes, int n_in,
                              void* d_out, int out_size, void* d_ws, size_t ws_size,
                              hipStream_t stream) {
    const float* x   = (const float*)d_in[0];
    const float* W   = (const float*)d_in[1];
    const float* U   = (const float*)d_in[2];
    const float* b   = (const float*)d_in[3];
    const float* tau = (const float*)d_in[4];
    const float* s   = (const float*)d_in[5];
    const float* lng = (const float*)d_in[6];
    const float* lnb = (const float*)d_in[7];
    const float* W1  = (const float*)d_in[8];
    const float* b1  = (const float*)d_in[9];
    const float* W2  = (const float*)d_in[10];
    const float* b2  = (const float*)d_in[11];
    float* out = (float*)d_out;
    plstm_scan_kernel<<<dim3(NB), dim3(NT), 0, stream>>>(
        x, W, U, b, tau, s, lng, lnb, W1, b1, W2, b2, out);
}

// Round 9
// 851.840 us; speedup vs baseline: 1.0532x; 1.0532x over previous
//
#include <hip/hip_runtime.h>
#include <cmath>

#define NB 256            // 16 batch groups x 16 unit blocks -> 1 block/CU (latency-chain regime)
#define NT 512
#define NG 16             // batch groups
#define GB 16             // blocks per group
#define B_ 256
#define T_ 256
#define I_ 64
#define H_ 512
#define G4H 2048
#define BT 16             // batch rows per block
#define UT 32             // hidden units per block -> 128 z cols, 8 waves
#define ZP 132            // zs row stride (128 + 4)
#define NFC 18            // K chunks of 32
#define CPQ 17            // cells (16B) per q-group: 16 rows + 1 pad
#define CSTR 68           // cell stride per chunk (4*17)
#define NCELL 1224        // 18*68
#define R_ON_F 0.05f
#define ALPHA_F 1.0e-3f
#define LN_EPS_F 1.0e-5f

typedef _Float16 h8 __attribute__((ext_vector_type(8)));
typedef _Float16 h4v __attribute__((ext_vector_type(4)));
typedef float f4 __attribute__((ext_vector_type(4)));
typedef unsigned u4 __attribute__((ext_vector_type(4)));
typedef unsigned short us4 __attribute__((ext_vector_type(4)));

// Packed hidden-state double buffer: fp16(h)<<16 | (launch_tag<<8 | t+1).
// DEVICE SCOPE ONLY (sc0 sc1): R4/R5 proved XCD co-location can't be assumed
// and L2-scope polling reads stale clean lines forever.
// Launch-tagged epochs (verified R7): stale data never equality-matches ->
// no zeroing, no startup barrier. NB=256 => tag = cnt>>8.
// STORE LAYOUT IS SACRED (R6 lesson): gate thread (urow,uu) => each wave
// stores 2 rows x 128B contiguous; scattering this doubled WRITE_SIZE.
// LATENCY-CHAIN FRAME (R8 lesson): 2 chains/CU cannot shorten the per-step
// critical path, only contend -- optimize path cycles, not throughput.
__device__ __align__(16) unsigned g_hp[2][B_ * H_];
// Exact fp32 final h for the LN/dense epilogue (written only at t = T_-1).
__device__ __align__(16) float g_hf[B_ * H_];

struct alignas(256) PadCnt { unsigned v; unsigned pad[63]; };
__device__ PadCnt g_flag[NG][GB];   // FINAL handoff only; tagged values
__device__ unsigned g_launch_cnt;   // never reset; +NB per launch => tag = cnt>>8

__device__ __forceinline__ float fast_sigmoid(float x) {
    return __builtin_amdgcn_rcpf(1.f + __expf(-x));
}
__device__ __forceinline__ float fast_tanh(float x) {
    return 1.f - 2.f * __builtin_amdgcn_rcpf(__expf(2.f * x) + 1.f);
}

struct HiLo { _Float16 hi, lo; };
__device__ __forceinline__ HiLo cvt_hilo(float v) {
    HiLo r;
    r.hi = (_Float16)v;
    r.lo = (_Float16)(v - (float)r.hi);
    return r;
}

__global__ __launch_bounds__(NT, 1) void plstm_scan_kernel(
    const float* __restrict__ x, const float* __restrict__ W,
    const float* __restrict__ U, const float* __restrict__ bias,
    const float* __restrict__ tau, const float* __restrict__ sph,
    const float* __restrict__ ln_g, const float* __restrict__ ln_b,
    const float* __restrict__ W1, const float* __restrict__ b1,
    const float* __restrict__ W2, const float* __restrict__ b2,
    float* __restrict__ out)
{
    __shared__ __align__(16) _Float16 Ah[NCELL * 8];   // 19.1 KB A (fp16 hi), fragment order
    __shared__ __align__(16) float zs[BT][ZP];         // 8.25 KB z tile
    __shared__ __align__(16) float kt[T_ * UT];        // 32 KB time-gate table
    __shared__ float red[16];
    __shared__ unsigned s_tag;

    const int tid = threadIdx.x;
    const int bt = blockIdx.x >> 4;    // batch group 0..15
    const int ut = blockIdx.x & 15;    // unit block 0..15
    const int b0 = bt * BT;
    const int u0 = ut * UT;

    if (tid == 0) s_tag = (atomicAdd(&g_launch_cnt, 1u) >> 8) + 1u;

    const int wv = tid >> 6;           // wave = N-tile 0..7
    const int lane = tid & 63;
    const int n_ = lane & 15;
    const int q_ = lane >> 4;

    // ---- one-time: B fragments (this wave's 16 cols), fp16 hi/lo ----
    const int jg = (wv >> 1) * 512 + u0 + (wv & 1) * 16 + n_;
    h8 Bh[NFC], Bl[NFC];
    #pragma unroll
    for (int c = 0; c < NFC; ++c) {
        #pragma unroll
        for (int e = 0; e < 8; ++e) {
            const int kk = c * 32 + q_ * 8 + e;
            float v;
            if (c < 2) v = W[(size_t)kk * G4H + jg];
            else       v = U[(size_t)(kk - I_) * G4H + jg];
            const HiLo hl = cvt_hilo(v);
            Bh[c][e] = hl.hi;
            Bl[c][e] = hl.lo;
        }
    }
    const float bv = bias[jg];         // bias folded into MFMA C-input

    // ---- one-time: time-gate table k[t][unit_local] (data-independent) ----
    for (int idx = tid; idx < T_ * UT; idx += NT) {
        const int tt = idx >> 5, ul = idx & 31;
        const float ta = tau[u0 + ul];
        float aa = (float)tt - sph[u0 + ul];
        float rr = fmodf(aa, ta);
        if (rr < 0.f) rr += ta;
        const float phi = rr / ta;
        float kk;
        if (phi < 0.5f * R_ON_F)      kk = phi * (2.f / R_ON_F);
        else if (phi < R_ON_F)        kk = 2.f - phi * (2.f / R_ON_F);
        else                          kk = ALPHA_F * phi;
        kt[idx] = kk;
    }
    __syncthreads();                   // publish s_tag + kt
    const unsigned tagw = s_tag;
    const unsigned tagb = (tagw & 0xFFu) << 8;

    // gate-update layout: all 512 threads -> (row 0..15, unit 0..31)
    const int urow = tid >> 5;
    const int uu   = tid & 31;
    float c_st = 0.f;
    float h_st = 0.f;   // exact fp32 hprev: pure per-thread recurrence
    // own-chunk Ah slot for this gate thread (chunk 2+ut, q=uu>>3, e=uu&7)
    const int ownIdx = ((2 + ut) * CSTR + (uu >> 3) * CPQ + urow) * 8 + (uu & 7);

    // staging geometry
    const int xr = (tid >> 4) & 15, xc4 = (tid & 15) << 2;  // x: tid<256, 1 float4
    const int cX = (tid & 15) >> 3, qX = ((tid & 15) >> 1) & 3;
    const int e0x = (tid & 1) << 2;
    const int fX = (cX * CSTR + qX * CPQ + xr) * 8 + e0x;
    const int m = tid & 127;                                // h: 4 rows x 4 packed cols
    const int hr0 = tid >> 7;
    const int hk4 = m << 2;
    const int cS = 2 + (m >> 3), qS = (m >> 1) & 3;
    const int e0 = (m & 1) << 2;
    const int srcblk = m >> 3;                              // writer block of my 4 cols
    const bool need = (srcblk != ut);                       // own chunk staged locally

    float4 xv = *(const float4*)(x + ((size_t)(b0 + xr) * T_ + 0) * I_ + xc4);

    // MFMA A-frag read base (fragment order; same A broadcast to all 8 waves)
    const int fb = (q_ * CPQ + n_) * 8;

    int cur = 0;
    for (int t = 0; t < T_; ++t) {
        // ---- A) stage operands (tag-exact epoch poll, device scope) ----
        if (t == 0) {
            const h8 z8 = {};
            for (int idx = tid; idx < NCELL; idx += NT)
                *(h8*)&Ah[idx * 8] = z8;
            __syncthreads();
            if (tid < 256) {
                h4v xh;
                xh[0] = (_Float16)xv.x; xh[1] = (_Float16)xv.y;
                xh[2] = (_Float16)xv.z; xh[3] = (_Float16)xv.w;
                *(h4v*)&Ah[fX] = xh;
            }
        } else {
            const unsigned* hb = g_hp[cur] + (size_t)(b0 + hr0) * H_ + hk4;
            const unsigned want = tagb | (unsigned)t;
            u4 a0, a1, a2, a3;
            bool ok = !need;           // own-chunk lanes: nothing to poll
            do {
                if (!ok) {
                    asm volatile(
                        "global_load_dwordx4 %0, %4, off sc0 sc1\n\t"
                        "global_load_dwordx4 %1, %5, off sc0 sc1\n\t"
                        "global_load_dwordx4 %2, %6, off sc0 sc1\n\t"
                        "global_load_dwordx4 %3, %7, off sc0 sc1\n\t"
                        "s_waitcnt vmcnt(0)"
                        : "=&v"(a0), "=&v"(a1), "=&v"(a2), "=&v"(a3)
                        : "v"(hb), "v"(hb + 4 * H_), "v"(hb + 8 * H_), "v"(hb + 12 * H_)
                        : "memory");
                    ok = ((a0[0] & 0xFFFFu) == want) & ((a0[1] & 0xFFFFu) == want)
                       & ((a0[2] & 0xFFFFu) == want) & ((a0[3] & 0xFFFFu) == want)
                       & ((a1[0] & 0xFFFFu) == want) & ((a1[1] & 0xFFFFu) == want)
                       & ((a1[2] & 0xFFFFu) == want) & ((a1[3] & 0xFFFFu) == want)
                       & ((a2[0] & 0xFFFFu) == want) & ((a2[1] & 0xFFFFu) == want)
                       & ((a2[2] & 0xFFFFu) == want) & ((a2[3] & 0xFFFFu) == want)
                       & ((a3[0] & 0xFFFFu) == want) & ((a3[1] & 0xFFFFu) == want)
                       & ((a3[2] & 0xFFFFu) == want) & ((a3[3] & 0xFFFFu) == want);
                }
            } while (__ballot(!ok));
            if (need) {
                const u4 av[4] = {a0, a1, a2, a3};
                #pragma unroll
                for (int it = 0; it < 4; ++it) {
                    const int row = hr0 + 4 * it;
                    const int fidx = (cS * CSTR + qS * CPQ + row) * 8 + e0;
                    us4 uv;
                    uv[0] = (unsigned short)(av[it][0] >> 16);
                    uv[1] = (unsigned short)(av[it][1] >> 16);
                    uv[2] = (unsigned short)(av[it][2] >> 16);
                    uv[3] = (unsigned short)(av[it][3] >> 16);
                    *(us4*)&Ah[fidx] = uv;   // fp16 payload, writer already converted
                }
            }
        }
        __syncthreads();                                   // S1

        // prefetch next x
        if (tid < 256) {
            const int tn = (t < T_ - 1) ? t + 1 : t;
            xv = *(const float4*)(x + ((size_t)(b0 + xr) * T_ + tn) * I_ + xc4);
        }

        // ---- B) MFMA: A-hi x (B-hi + B-lo), bias as C-in, 4 acc chains ----
        f4 ac0 = {bv, bv, bv, bv};
        f4 ac0b = {0.f, 0.f, 0.f, 0.f};
        f4 ac1 = {0.f, 0.f, 0.f, 0.f};
        f4 ac1b = {0.f, 0.f, 0.f, 0.f};
        #pragma unroll
        for (int c = 0; c < NFC; c += 2) {
            const h8 ah0 = *(const h8*)&Ah[fb + c * (CSTR * 8)];
            const h8 ah1 = *(const h8*)&Ah[fb + (c + 1) * (CSTR * 8)];
            ac0  = __builtin_amdgcn_mfma_f32_16x16x32_f16(ah0, Bh[c],     ac0,  0, 0, 0);
            ac1  = __builtin_amdgcn_mfma_f32_16x16x32_f16(ah0, Bl[c],     ac1,  0, 0, 0);
            ac0b = __builtin_amdgcn_mfma_f32_16x16x32_f16(ah1, Bh[c + 1], ac0b, 0, 0, 0);
            ac1b = __builtin_amdgcn_mfma_f32_16x16x32_f16(ah1, Bl[c + 1], ac1b, 0, 0, 0);
        }
        const f4 zt = (ac0 + ac0b) + (ac1 + ac1b);
        {
            const int colz = wv * 16 + n_;
            const int rz = q_ * 4;     // C-layout: row=(lane>>4)*4+reg (M=16)
            zs[rz + 0][colz] = zt[0];
            zs[rz + 1][colz] = zt[1];
            zs[rz + 2][colz] = zt[2];
            zs[rz + 3][colz] = zt[3];
        }
        __syncthreads();                                   // S2

        // ---- C) gates + table time-gate; tagged h store + own-chunk LDS stage ----
        {
            const float zi = zs[urow][uu];
            const float zf = zs[urow][32 + uu];
            const float zg = zs[urow][64 + uu];
            const float zo = zs[urow][96 + uu];
            const float si = fast_sigmoid(zi);
            const float sf = fast_sigmoid(zf);
            const float so = fast_sigmoid(zo);
            const float ct = sf * c_st + si * fast_tanh(zg);
            const float ht = so * fast_tanh(ct);
            const float kk = kt[(t << 5) + uu];
            const float hn = kk * ht + (1.f - kk) * h_st;
            c_st = kk * ct + (1.f - kk) * c_st;
            h_st = hn;
            const _Float16 hn16 = (_Float16)hn;
            if (t < T_ - 1) {
                const unsigned short hb16 = __builtin_bit_cast(unsigned short, hn16);
                const unsigned packed = ((unsigned)hb16 << 16) | (tagb | (unsigned)(t + 1));
                unsigned* gp = g_hp[cur ^ 1] + (size_t)(b0 + urow) * H_ + (u0 + uu);
                asm volatile("global_store_dword %0, %1, off sc0 sc1"
                             :: "v"(gp), "v"(packed) : "memory");
                // own-chunk staging: write fp16(hn) straight into next step's
                // Ah slot (bit-identical to the packed>>16 path). S2 above
                // separates it from this step's MFMA reads of the same cells.
                Ah[ownIdx] = hn16;
            } else {
                float* gp = g_hf + (size_t)(b0 + urow) * H_ + (u0 + uu);
                asm volatile("global_store_dword %0, %1, off sc0 sc1\n\ts_waitcnt vmcnt(0)"
                             :: "v"(gp), "v"(hn) : "memory");
            }
        }

        // ---- final-step handoff: drain + barrier + tagged flag publish ----
        if (t == T_ - 1) {
            __syncthreads();
            if (tid == 0) {
                unsigned fv = (tagw << 8) | 0xFFu;
                asm volatile("global_store_dword %0, %1, off sc0 sc1"
                             :: "v"(&g_flag[bt][ut].v), "v"(fv) : "memory");
            }
        }

        // ---- D) overlapped x staging ----
        if (t < T_ - 1 && tid < 256) {
            h4v xh;
            xh[0] = (_Float16)xv.x; xh[1] = (_Float16)xv.y;
            xh[2] = (_Float16)xv.z; xh[3] = (_Float16)xv.w;
            *(h4v*)&Ah[fX] = xh;
        }
        cur ^= 1;
    }

    // ---- epilogue: block (bt,ut) handles batch row b0+ut: LN + dense head ----
    {
        if (tid < 64) {
            const unsigned want = (tagw << 8) | 0xFFu;
            const unsigned* fp = &g_flag[bt][tid & 15].v;
            unsigned v;
            do {
                asm volatile("global_load_dword %0, %1, off sc0 sc1\n\ts_waitcnt vmcnt(0)"
                             : "=v"(v) : "v"(fp) : "memory");
            } while (__ballot(v != want));
        }
        __syncthreads();

        const int r = b0 + ut;         // bijective over [0,256)
        float hv;
        const float* hp = g_hf + (size_t)r * H_ + tid;
        asm volatile("global_load_dword %0, %1, off sc0 sc1\n\ts_waitcnt vmcnt(0)"
                     : "=v"(hv) : "v"(hp) : "memory");
        float s1 = hv, s2 = hv * hv;
        #pragma unroll
        for (int off = 32; off > 0; off >>= 1) {
            s1 += __shfl_down(s1, off, 64);
            s2 += __shfl_down(s2, off, 64);
        }
        const int ln = tid & 63;
        if (ln == 0) { red[wv] = s1; red[8 + wv] = s2; }
        __syncthreads();
        float S1 = 0.f, S2 = 0.f;
        #pragma unroll
        for (int w = 0; w < 8; ++w) { S1 += red[w]; S2 += red[8 + w]; }
        const float mu = S1 * (1.f / 512.f);
        const float var = S2 * (1.f / 512.f) - mu * mu;
        const float rstd = rsqrtf(var + LN_EPS_F);
        const float hn = (hv - mu) * rstd * ln_g[tid] + ln_b[tid];
        float w12 = 0.f;
        const float* w1p = W1 + (size_t)tid * 256;
        #pragma unroll 4
        for (int d = 0; d < 256; ++d) w12 = fmaf(w1p[d], W2[d], w12);
        float contrib = hn * w12;
        if (tid < 256) contrib = fmaf(b1[tid], W2[tid], contrib);
        #pragma unroll
        for (int off = 32; off > 0; off >>= 1) contrib += __shfl_down(contrib, off, 64);
        __syncthreads();
        if (ln == 0) red[wv] = contrib;
        __syncthreads();
        if (tid == 0) {
            float tot = b2[0];
            #pragma unroll
            for (int w = 0; w < 8; ++w) tot += red[w];
            out[r] = tot;
        }
    }
}

extern "C" void kernel_launch(void* const* d_in, const int* in_sizes, int n_in,
                              void* d_out, int out_size, void* d_ws, size_t ws_size,
                              hipStream_t stream) {
    const float* x   = (const float*)d_in[0];
    const float* W   = (const float*)d_in[1];
    const float* U   = (const float*)d_in[2];
    const float* b   = (const float*)d_in[3];
    const float* tau = (const float*)d_in[4];
    const float* s   = (const float*)d_in[5];
    const float* lng = (const float*)d_in[6];
    const float* lnb = (const float*)d_in[7];
    const float* W1  = (const float*)d_in[8];
    const float* b1  = (const float*)d_in[9];
    const float* W2  = (const float*)d_in[10];
    const float* b2  = (const float*)d_in[11];
    float* out = (float*)d_out;
    plstm_scan_kernel<<<dim3(NB), dim3(NT), 0, stream>>>(
        x, W, U, b, tau, s, lng, lnb, W1, b1, W2, b2, out);
}

// Round 10
// 763.505 us; speedup vs baseline: 1.1751x; 1.1157x over previous
//
#include <hip/hip_runtime.h>
#include <cmath>

#define NB 256            // 16 batch groups x 16 unit blocks -> 1 block/CU (latency-chain regime)
#define NT 512
#define NG 16             // batch groups
#define GB 16             // blocks per group
#define B_ 256
#define T_ 256
#define I_ 64
#define H_ 512
#define G4H 2048
#define BT 16             // batch rows per block
#define UT 32             // hidden units per block -> 128 z cols, 8 waves
#define ZP 132            // zs row stride (128 + 4)
#define NFC 18            // K chunks of 32
#define CPQ 17            // cells (16B) per q-group: 16 rows + 1 pad
#define CSTR 68           // cell stride per chunk (4*17)
#define NCELL 1224        // 18*68
#define R_ON_F 0.05f
#define ALPHA_F 1.0e-3f
#define LN_EPS_F 1.0e-5f

typedef _Float16 h8 __attribute__((ext_vector_type(8)));
typedef _Float16 h4v __attribute__((ext_vector_type(4)));
typedef float f4 __attribute__((ext_vector_type(4)));
typedef unsigned u4 __attribute__((ext_vector_type(4)));
typedef unsigned short us4 __attribute__((ext_vector_type(4)));

// Packed hidden-state double buffer: fp16(h)<<16 | (launch_tag<<8 | t+1).
// DEVICE SCOPE ONLY (sc0 sc1): R4/R5 proved XCD co-location can't be assumed
// and L2-scope polling reads stale clean lines forever.
// Launch-tagged epochs (verified R7): stale data never equality-matches ->
// no zeroing, no startup barrier. NB=256 => tag = cnt>>8.
// STORE LAYOUT IS SACRED (R6): gate thread (urow,uu) => each wave stores
// 2 rows x 128B contiguous; scattering doubled WRITE_SIZE and cost 2x.
// LATENCY-CHAIN FRAME (R8): extra chains/CU contend, never shorten the path.
// POLL LOOP IS SACRED (R9): divergent own-chunk skip + extra LDS write in
// the gate phase cost +80us; polls are IF$-served (FETCH unmoved), so
// skipping loads saves nothing.
__device__ __align__(16) unsigned g_hp[2][B_ * H_];
// Exact fp32 final h for the LN/dense epilogue (written only at t = T_-1).
__device__ __align__(16) float g_hf[B_ * H_];

struct alignas(256) PadCnt { unsigned v; unsigned pad[63]; };
__device__ PadCnt g_flag[NG][GB];   // FINAL handoff only; tagged values
__device__ unsigned g_launch_cnt;   // never reset; +NB per launch => tag = cnt>>8

__device__ __forceinline__ float fast_sigmoid(float x) {
    return __builtin_amdgcn_rcpf(1.f + __expf(-x));
}
__device__ __forceinline__ float fast_tanh(float x) {
    return 1.f - 2.f * __builtin_amdgcn_rcpf(__expf(2.f * x) + 1.f);
}

struct HiLo { _Float16 hi, lo; };
__device__ __forceinline__ HiLo cvt_hilo(float v) {
    HiLo r;
    r.hi = (_Float16)v;
    r.lo = (_Float16)(v - (float)r.hi);
    return r;
}

__global__ __launch_bounds__(NT, 1) void plstm_scan_kernel(
    const float* __restrict__ x, const float* __restrict__ W,
    const float* __restrict__ U, const float* __restrict__ bias,
    const float* __restrict__ tau, const float* __restrict__ sph,
    const float* __restrict__ ln_g, const float* __restrict__ ln_b,
    const float* __restrict__ W1, const float* __restrict__ b1,
    const float* __restrict__ W2, const float* __restrict__ b2,
    float* __restrict__ out)
{
    __shared__ __align__(16) _Float16 Ah[NCELL * 8];   // 19.1 KB A (fp16 hi), fragment order
    __shared__ __align__(16) float zs[BT][ZP];         // 8.25 KB z tile
    __shared__ __align__(16) float kt[T_ * UT];        // 32 KB time-gate table
    __shared__ float red[16];
    __shared__ unsigned s_tag;

    const int tid = threadIdx.x;
    const int bt = blockIdx.x >> 4;    // batch group 0..15
    const int ut = blockIdx.x & 15;    // unit block 0..15
    const int b0 = bt * BT;
    const int u0 = ut * UT;

    if (tid == 0) s_tag = (atomicAdd(&g_launch_cnt, 1u) >> 8) + 1u;

    const int wv = tid >> 6;           // wave = N-tile 0..7
    const int lane = tid & 63;
    const int n_ = lane & 15;
    const int q_ = lane >> 4;

    // ---- one-time: B fragments (this wave's 16 cols), fp16 hi/lo ----
    const int jg = (wv >> 1) * 512 + u0 + (wv & 1) * 16 + n_;
    h8 Bh[NFC], Bl[NFC];
    #pragma unroll
    for (int c = 0; c < NFC; ++c) {
        #pragma unroll
        for (int e = 0; e < 8; ++e) {
            const int kk = c * 32 + q_ * 8 + e;
            float v;
            if (c < 2) v = W[(size_t)kk * G4H + jg];
            else       v = U[(size_t)(kk - I_) * G4H + jg];
            const HiLo hl = cvt_hilo(v);
            Bh[c][e] = hl.hi;
            Bl[c][e] = hl.lo;
        }
    }
    const float bv = bias[jg];         // bias folded into MFMA C-input

    // ---- one-time: time-gate table k[t][unit_local] (data-independent) ----
    for (int idx = tid; idx < T_ * UT; idx += NT) {
        const int tt = idx >> 5, ul = idx & 31;
        const float ta = tau[u0 + ul];
        float aa = (float)tt - sph[u0 + ul];
        float rr = fmodf(aa, ta);
        if (rr < 0.f) rr += ta;
        const float phi = rr / ta;
        float kk;
        if (phi < 0.5f * R_ON_F)      kk = phi * (2.f / R_ON_F);
        else if (phi < R_ON_F)        kk = 2.f - phi * (2.f / R_ON_F);
        else                          kk = ALPHA_F * phi;
        kt[idx] = kk;
    }
    __syncthreads();                   // publish s_tag + kt
    const unsigned tagw = s_tag;
    const unsigned tagb = (tagw & 0xFFu) << 8;

    // gate-update layout: all 512 threads -> (row 0..15, unit 0..31)
    const int urow = tid >> 5;
    const int uu   = tid & 31;
    float c_st = 0.f;
    float h_st = 0.f;   // exact fp32 hprev: pure per-thread recurrence

    // staging geometry
    const int xr = (tid >> 4) & 15, xc4 = (tid & 15) << 2;  // x: tid<256, 1 float4
    const int cX = (tid & 15) >> 3, qX = ((tid & 15) >> 1) & 3;
    const int e0x = (tid & 1) << 2;
    const int fX = (cX * CSTR + qX * CPQ + xr) * 8 + e0x;
    const int m = tid & 127;                                // h: 4 rows x 4 packed cols
    const int hr0 = tid >> 7;
    const int hk4 = m << 2;
    const int cS = 2 + (m >> 3), qS = (m >> 1) & 3;
    const int e0 = (m & 1) << 2;

    float4 xv = *(const float4*)(x + ((size_t)(b0 + xr) * T_ + 0) * I_ + xc4);

    // MFMA A-frag read base (fragment order; same A broadcast to all 8 waves)
    const int fb = (q_ * CPQ + n_) * 8;

    int cur = 0;
    for (int t = 0; t < T_; ++t) {
        // ---- A) stage operands (tag-exact epoch poll, device scope) ----
        if (t == 0) {
            const h8 z8 = {};
            for (int idx = tid; idx < NCELL; idx += NT)
                *(h8*)&Ah[idx * 8] = z8;
            __syncthreads();
            if (tid < 256) {
                h4v xh;
                xh[0] = (_Float16)xv.x; xh[1] = (_Float16)xv.y;
                xh[2] = (_Float16)xv.z; xh[3] = (_Float16)xv.w;
                *(h4v*)&Ah[fX] = xh;
            }
        } else {
            const unsigned* hb = g_hp[cur] + (size_t)(b0 + hr0) * H_ + hk4;
            const unsigned want = tagb | (unsigned)t;
            u4 a0, a1, a2, a3;
            bool ok;
            do {
                asm volatile(
                    "global_load_dwordx4 %0, %4, off sc0 sc1\n\t"
                    "global_load_dwordx4 %1, %5, off sc0 sc1\n\t"
                    "global_load_dwordx4 %2, %6, off sc0 sc1\n\t"
                    "global_load_dwordx4 %3, %7, off sc0 sc1\n\t"
                    "s_waitcnt vmcnt(0)"
                    : "=&v"(a0), "=&v"(a1), "=&v"(a2), "=&v"(a3)
                    : "v"(hb), "v"(hb + 4 * H_), "v"(hb + 8 * H_), "v"(hb + 12 * H_)
                    : "memory");
                ok = ((a0[0] & 0xFFFFu) == want) & ((a0[1] & 0xFFFFu) == want)
                   & ((a0[2] & 0xFFFFu) == want) & ((a0[3] & 0xFFFFu) == want)
                   & ((a1[0] & 0xFFFFu) == want) & ((a1[1] & 0xFFFFu) == want)
                   & ((a1[2] & 0xFFFFu) == want) & ((a1[3] & 0xFFFFu) == want)
                   & ((a2[0] & 0xFFFFu) == want) & ((a2[1] & 0xFFFFu) == want)
                   & ((a2[2] & 0xFFFFu) == want) & ((a2[3] & 0xFFFFu) == want)
                   & ((a3[0] & 0xFFFFu) == want) & ((a3[1] & 0xFFFFu) == want)
                   & ((a3[2] & 0xFFFFu) == want) & ((a3[3] & 0xFFFFu) == want);
            } while (__ballot(!ok));
            const u4 av[4] = {a0, a1, a2, a3};
            #pragma unroll
            for (int it = 0; it < 4; ++it) {
                const int row = hr0 + 4 * it;
                const int fidx = (cS * CSTR + qS * CPQ + row) * 8 + e0;
                us4 uv;
                uv[0] = (unsigned short)(av[it][0] >> 16);
                uv[1] = (unsigned short)(av[it][1] >> 16);
                uv[2] = (unsigned short)(av[it][2] >> 16);
                uv[3] = (unsigned short)(av[it][3] >> 16);
                *(us4*)&Ah[fidx] = uv;   // fp16 payload, writer already converted
            }
        }
        __syncthreads();                                   // S1

        // prefetch next x
        if (tid < 256) {
            const int tn = (t < T_ - 1) ? t + 1 : t;
            xv = *(const float4*)(x + ((size_t)(b0 + xr) * T_ + tn) * I_ + xc4);
        }

        // ---- B) MFMA: A-hi x (B-hi + B-lo), bias as C-in ----
        f4 ac0 = {bv, bv, bv, bv};
        f4 ac1 = {0.f, 0.f, 0.f, 0.f};
        #pragma unroll
        for (int c = 0; c < NFC; ++c) {
            const h8 ah = *(const h8*)&Ah[fb + c * (CSTR * 8)];
            ac0 = __builtin_amdgcn_mfma_f32_16x16x32_f16(ah, Bh[c], ac0, 0, 0, 0);
            ac1 = __builtin_amdgcn_mfma_f32_16x16x32_f16(ah, Bl[c], ac1, 0, 0, 0);
        }
        const f4 zt = ac0 + ac1;
        {
            const int colz = wv * 16 + n_;
            const int rz = q_ * 4;     // C-layout: row=(lane>>4)*4+reg (M=16)
            zs[rz + 0][colz] = zt[0];
            zs[rz + 1][colz] = zt[1];
            zs[rz + 2][colz] = zt[2];
            zs[rz + 3][colz] = zt[3];
        }
        __syncthreads();                                   // S2

        // ---- C) gates + table time-gate; tagged h store (coalesced layout) ----
        {
            const float zi = zs[urow][uu];
            const float zf = zs[urow][32 + uu];
            const float zg = zs[urow][64 + uu];
            const float zo = zs[urow][96 + uu];
            const float si = fast_sigmoid(zi);
            const float sf = fast_sigmoid(zf);
            const float so = fast_sigmoid(zo);
            const float ct = sf * c_st + si * fast_tanh(zg);
            const float ht = so * fast_tanh(ct);
            const float kk = kt[(t << 5) + uu];
            const float hn = kk * ht + (1.f - kk) * h_st;
            c_st = kk * ct + (1.f - kk) * c_st;
            h_st = hn;
            if (t < T_ - 1) {
                const unsigned short hb16 = __builtin_bit_cast(unsigned short, (_Float16)hn);
                const unsigned packed = ((unsigned)hb16 << 16) | (tagb | (unsigned)(t + 1));
                unsigned* gp = g_hp[cur ^ 1] + (size_t)(b0 + urow) * H_ + (u0 + uu);
                asm volatile("global_store_dword %0, %1, off sc0 sc1"
                             :: "v"(gp), "v"(packed) : "memory");
            } else {
                float* gp = g_hf + (size_t)(b0 + urow) * H_ + (u0 + uu);
                asm volatile("global_store_dword %0, %1, off sc0 sc1\n\ts_waitcnt vmcnt(0)"
                             :: "v"(gp), "v"(hn) : "memory");
            }
        }

        // ---- final-step handoff: drain + barrier + tagged flag publish ----
        if (t == T_ - 1) {
            __syncthreads();
            if (tid == 0) {
                unsigned fv = (tagw << 8) | 0xFFu;
                asm volatile("global_store_dword %0, %1, off sc0 sc1"
                             :: "v"(&g_flag[bt][ut].v), "v"(fv) : "memory");
            }
        }

        // ---- D) overlapped x staging ----
        if (t < T_ - 1 && tid < 256) {
            h4v xh;
            xh[0] = (_Float16)xv.x; xh[1] = (_Float16)xv.y;
            xh[2] = (_Float16)xv.z; xh[3] = (_Float16)xv.w;
            *(h4v*)&Ah[fX] = xh;
        }
        cur ^= 1;
    }

    // ---- epilogue: block (bt,ut) handles batch row b0+ut: LN + dense head ----
    {
        if (tid < 64) {
            const unsigned want = (tagw << 8) | 0xFFu;
            const unsigned* fp = &g_flag[bt][tid & 15].v;
            unsigned v;
            do {
                asm volatile("global_load_dword %0, %1, off sc0 sc1\n\ts_waitcnt vmcnt(0)"
                             : "=v"(v) : "v"(fp) : "memory");
            } while (__ballot(v != want));
        }
        __syncthreads();

        const int r = b0 + ut;         // bijective over [0,256)
        float hv;
        const float* hp = g_hf + (size_t)r * H_ + tid;
        asm volatile("global_load_dword %0, %1, off sc0 sc1\n\ts_waitcnt vmcnt(0)"
                     : "=v"(hv) : "v"(hp) : "memory");
        float s1 = hv, s2 = hv * hv;
        #pragma unroll
        for (int off = 32; off > 0; off >>= 1) {
            s1 += __shfl_down(s1, off, 64);
            s2 += __shfl_down(s2, off, 64);
        }
        const int ln = tid & 63;
        if (ln == 0) { red[wv] = s1; red[8 + wv] = s2; }
        __syncthreads();
        float S1 = 0.f, S2 = 0.f;
        #pragma unroll
        for (int w = 0; w < 8; ++w) { S1 += red[w]; S2 += red[8 + w]; }
        const float mu = S1 * (1.f / 512.f);
        const float var = S2 * (1.f / 512.f) - mu * mu;
        const float rstd = rsqrtf(var + LN_EPS_F);
        const float hn = (hv - mu) * rstd * ln_g[tid] + ln_b[tid];
        float w12 = 0.f;
        const float* w1p = W1 + (size_t)tid * 256;
        #pragma unroll 4
        for (int d = 0; d < 256; ++d) w12 = fmaf(w1p[d], W2[d], w12);
        float contrib = hn * w12;
        if (tid < 256) contrib = fmaf(b1[tid], W2[tid], contrib);
        #pragma unroll
        for (int off = 32; off > 0; off >>= 1) contrib += __shfl_down(contrib, off, 64);
        __syncthreads();
        if (ln == 0) red[wv] = contrib;
        __syncthreads();
        if (tid == 0) {
            float tot = b2[0];
            #pragma unroll
            for (int w = 0; w < 8; ++w) tot += red[w];
            out[r] = tot;
        }
    }
}

extern "C" void kernel_launch(void* const* d_in, const int* in_sizes, int n_in,
                              void* d_out, int out_size, void* d_ws, size_t ws_size,
                              hipStream_t stream) {
    const float* x   = (const float*)d_in[0];
    const float* W   = (const float*)d_in[1];
    const float* U   = (const float*)d_in[2];
    const float* b   = (const float*)d_in[3];
    const float* tau = (const float*)d_in[4];
    const float* s   = (const float*)d_in[5];
    const float* lng = (const float*)d_in[6];
    const float* lnb = (const float*)d_in[7];
    const float* W1  = (const float*)d_in[8];
    const float* b1  = (const float*)d_in[9];
    const float* W2  = (const float*)d_in[10];
    const float* b2  = (const float*)d_in[11];
    float* out = (float*)d_out;
    plstm_scan_kernel<<<dim3(NB), dim3(NT), 0, stream>>>(
        x, W, U, b, tau, s, lng, lnb, W1, b1, W2, b2, out);
}